// Round 13
// baseline (147.217 us; speedup 1.0000x reference)
//
#include <hip/hip_runtime.h>
#include <hip/hip_bf16.h>
#include <stdint.h>

#define LN_EPS 1e-5f

typedef __attribute__((ext_vector_type(4))) float f32x4;
typedef __attribute__((ext_vector_type(8))) short bf16x8;

#define D_ 1024
#define P_ 512
#define N_ 32768   // B*S rows

// async global->LDS, 16B per lane
__device__ __forceinline__ void gload_lds16(const void* gsrc, void* ldst) {
  __builtin_amdgcn_global_load_lds(
      (const __attribute__((address_space(1))) void*)gsrc,
      (__attribute__((address_space(3))) void*)ldst,
      16, 0, 0);
}

__device__ __forceinline__ short f2bf(float x) {
  union { __hip_bfloat16 h; short s; } u; u.h = __float2bfloat16(x); return u.s;
}

// ---------------- fused pre-kernel: [0,1024) = W2 build, [1024,33792) = LN ----------------
// W2 path (block c): s5 partitions d-space (each d maps to exactly one c), so
// block c finds its own d-list with a parallel LDS scan (4 d's/thread, LDS
// atomics -> <=32 entries), then sums the matching W rows coalesced and writes
// w2b (bf16) + b2 directly. W is read exactly once device-wide. No global
// atomics, no memset, no fp32 intermediate buffer.
// LN path (block 1024+n): identical to the proven round-6 k_ln_gather.
// The 1024 W2 blocks dispatch first and hide under the 32768-block LN stream.
__global__ __launch_bounds__(256) void k_pre(
    const float* __restrict__ x,      // hidden_states [N_,D_]
    const float* __restrict__ lnw, const float* __restrict__ lnb,
    const int* __restrict__ s3,
    const float* __restrict__ W,      // [D_,P_]
    const float* __restrict__ bias,   // [D_]
    const int* __restrict__ s5,       // [D_]
    __hip_bfloat16* __restrict__ g,   // out: [N_,P_]
    __hip_bfloat16* __restrict__ w2b, // out: [D_,P_]
    float* __restrict__ b2) {         // out: [D_]
  __shared__ int ibuf[1024];          // s5 copy (w2 path) / f32 row (ln path)
  __shared__ float psum[4], psum2[4];
  __shared__ int list[32];
  __shared__ int cnt;
  const int bid = blockIdx.x;
  const int t = threadIdx.x;

  if (bid < 1024) {
    // ===== W2 build path =====
    const int c = bid;
    if (t == 0) cnt = 0;
    #pragma unroll
    for (int i = 0; i < 4; ++i) ibuf[t + i * 256] = s5[t + i * 256];
    __syncthreads();
    #pragma unroll
    for (int i = 0; i < 4; ++i) {
      const int d = t + i * 256;
      if (ibuf[d] == c) { const int p = atomicAdd(&cnt, 1); list[p] = d; }
    }
    __syncthreads();
    const int k = cnt;
    float a0 = 0.f, a1 = 0.f, bb = 0.f;
    for (int j = 0; j < k; ++j) {
      const int d = list[j];
      const float2 wv = ((const float2*)(W + (size_t)d * P_))[t];  // cols 2t,2t+1
      a0 += wv.x; a1 += wv.y; bb += bias[d];
    }
    const unsigned lo = (unsigned short)f2bf(a0);
    const unsigned hi = (unsigned short)f2bf(a1);
    ((unsigned int*)w2b)[c * 256 + t] = lo | (hi << 16);
    if (t == 0) b2[c] = bb;
  } else {
    // ===== LayerNorm + gather path (round-6 proven) =====
    const int n = bid - 1024;
    float* row = (float*)ibuf;
    const float* xr = x + (size_t)n * D_;
    float4 v = ((const float4*)xr)[t];     // 256 threads * 4 floats = 1024
    ((float4*)row)[t] = v;
    float s  = v.x + v.y + v.z + v.w;
    float s2 = v.x*v.x + v.y*v.y + v.z*v.z + v.w*v.w;
    #pragma unroll
    for (int off = 32; off > 0; off >>= 1) {
      s  += __shfl_down(s, off);
      s2 += __shfl_down(s2, off);
    }
    const int lane = t & 63, wid = t >> 6;
    if (lane == 0) { psum[wid] = s; psum2[wid] = s2; }
    __syncthreads();
    const float tot  = psum[0] + psum[1] + psum[2] + psum[3];
    const float tot2 = psum2[0] + psum2[1] + psum2[2] + psum2[3];
    const float mu  = tot * (1.f / D_);
    const float var = tot2 * (1.f / D_) - mu * mu;
    const float inv = rsqrtf(var + LN_EPS);
    __hip_bfloat16* gr = g + (size_t)n * P_;
    const int i0 = s3[2*t], i1 = s3[2*t+1];
    const float v0 = (row[i0] - mu) * inv * lnw[i0] + lnb[i0];
    const float v1 = (row[i1] - mu) * inv * lnw[i1] + lnb[i1];
    const unsigned lo = (unsigned short)f2bf(v0);
    const unsigned hi = (unsigned short)f2bf(v1);
    ((unsigned int*)gr)[t] = lo | (hi << 16);
  }
}

// ---------------- kernel: bf16 MFMA GEMM + residual + bias ----------------
// out[n,c] = hid[n,c] + sum_p g[n,p]*W2[c,p] + b2[c]
// 128x128 tile, BK=64, double-buffered LDS (64KB), 8 waves (2x4, 64x32 wave
// tile), 16x16x32 bf16 MFMA, acc 4x2.
// Round-8-proven counted-vmcnt manual-barrier loop, 2 tiles deep, PLUS the
// hid epilogue tile prefetched ONCE before the loop (after S0,S1 in program
// order) so all 8 HBM loads fly under the first compute steps and never
// couple to a barrier drain (round-10's __syncthreads forced vmcnt(0) on
// them 4x late in the loop).
// Issue order: S0(4) S1(4) HP(8); per step k: need S(k) done ->
//   k=0,1: vmcnt(12); k=2: vmcnt(4) (drains HP, ~2 steps of flight);
//   k=3..6: vmcnt(4) (r8 steady state); k=7: vmcnt(0).
// Epilogue: acc tile bounced through the dead 64KB LDS (128x128 f32), read
// back float4/lane -> out-store fully coalesced.
#define BM 128
#define BN 128
#define BK 64

#define WAITV(N) asm volatile("s_waitcnt vmcnt(" #N ")" ::: "memory")
#define WAITL0   asm volatile("s_waitcnt lgkmcnt(0)" ::: "memory")
#define SCHEDB   __builtin_amdgcn_sched_barrier(0)
#define BARR     __builtin_amdgcn_s_barrier()

__global__ __launch_bounds__(512, 4) void k_gemm(
    const __hip_bfloat16* __restrict__ g,    // [N_,P_]
    const __hip_bfloat16* __restrict__ w2b,  // [D_,P_]
    const float* __restrict__ b2,            // [D_]
    const float* __restrict__ hid,           // [N_,D_]
    float* __restrict__ out) {               // [N_,D_]
  __shared__ __align__(16) char smem[65536]; // At[2][16K] | Bt[2][16K] == ctile f32[128][128]
  char* At[2] = { smem,         smem + 16384 };
  char* Bt[2] = { smem + 32768, smem + 49152 };
  float* ctile = (float*)smem;

  // XCD-aware swizzle (proven: FETCH 202->132 MB): XCD x gets 32 contiguous
  // bm strips; the 8 bn-siblings of each strip stay on one XCD.
  const int bid = blockIdx.x;                // 0..2047
  const int x = bid & 7;
  const int kq = bid >> 3;                   // 0..255
  const int bm = (x * 32 + (kq >> 3)) * BM;
  const int bn = (kq & 7) * BN;

  const int t = threadIdx.x;
  const int lane = t & 63;
  const int wid = t >> 6;                    // 8 waves
  const int wr = wid >> 2, wc = wid & 3;     // 2x4 waves, 64x32 subtile each

  f32x4 acc[4][2] = {};
  f32x4 hp[8];                               // prefetched hid tile (32 VGPR)

  // stage tile ks into buf: per thread 2x(A,B) = 4 gload_lds, program-order
  // contiguous (the vmcnt-counting unit).
  #define STAGE(ks, buf)                                                      \
    {                                                                         \
      const int k0 = (ks) * BK;                                               \
      _Pragma("unroll")                                                       \
      for (int i = 0; i < 2; ++i) {                                           \
        int ch = t + i * 512;                 /* 0..1023 */                    \
        int r  = ch >> 3;                     /* tile row, 8 x 16B per 128B row */ \
        int cc = ch & 7;                                                      \
        int col = ((cc ^ (r & 7)) << 3);      /* pre-swizzled src col (bf16) */ \
        gload_lds16(g   + (size_t)(bm + r) * P_ + k0 + col, At[buf] + ch * 16); \
        gload_lds16(w2b + (size_t)(bn + r) * P_ + k0 + col, Bt[buf] + ch * 16); \
      }                                                                       \
    }

  STAGE(0, 0);
  STAGE(1, 1);
  // hid prefetch: all 8 f32x4 issued NOW (after S0,S1) -> in flight under
  // the first compute steps; drained by step 2's vmcnt(4).
  #pragma unroll
  for (int i = 0; i < 8; ++i) {
    const int idx = i * 512 + t;             // 0..4095 float4 slots
    const int row = idx >> 5;
    const int j0  = (idx & 31) << 2;
    hp[i] = __builtin_nontemporal_load(
        (const f32x4*)(hid + (size_t)(bm + row) * D_ + bn + j0));
  }

  #pragma unroll
  for (int ks = 0; ks < 8; ++ks) {
    const int buf = ks & 1;
    // wait for tile ks (keep later loads in flight; oldest-first semantics)
    if (ks <= 1)      { WAITV(12); }
    else if (ks == 7) { WAITV(0);  }
    else              { WAITV(4);  }
    SCHEDB;
    BARR;

    bf16x8 af[2][4], bfr[2][2];
    #pragma unroll
    for (int kk = 0; kk < 2; ++kk) {
      const int colb = kk * 64 + ((lane >> 4) << 4);   // byte offset in row
      #pragma unroll
      for (int mi = 0; mi < 4; ++mi) {
        const int r = wr * 64 + mi * 16 + (lane & 15);
        af[kk][mi] = *(const bf16x8*)(At[buf] + ((r * 128 + colb) ^ ((r & 7) << 4)));
      }
      #pragma unroll
      for (int ni = 0; ni < 2; ++ni) {
        const int r = wc * 32 + ni * 16 + (lane & 15);
        bfr[kk][ni] = *(const bf16x8*)(Bt[buf] + ((r * 128 + colb) ^ ((r & 7) << 4)));
      }
    }
    WAITL0;   // this wave's frags in regs
    SCHEDB;   // rule 18: keep MFMA below the waitcnt
    BARR;     // all waves done reading buf -> safe to re-stage it

    if (ks < 6) STAGE(ks + 2, buf);

    #pragma unroll
    for (int kk = 0; kk < 2; ++kk)
      #pragma unroll
      for (int mi = 0; mi < 4; ++mi)
        #pragma unroll
        for (int ni = 0; ni < 2; ++ni)
          acc[mi][ni] = __builtin_amdgcn_mfma_f32_16x16x32_bf16(
              af[kk][mi], bfr[kk][ni], acc[mi][ni], 0, 0, 0);
  }

  // ===== epilogue =====
  __syncthreads();   // full drain; smem becomes ctile
  // write acc fragments to ctile. C/D layout: col=lane&15, row=(lane>>4)*4+r4.
  // col-XOR ((row>>2)&1)<<4 splits the 4 lane-groups across banks 0-15/16-31
  // and preserves float4 contiguity on readback.
  #pragma unroll
  for (int ni = 0; ni < 2; ++ni) {
    #pragma unroll
    for (int mi = 0; mi < 4; ++mi) {
      #pragma unroll
      for (int r4 = 0; r4 < 4; ++r4) {
        const int row = wr * 64 + mi * 16 + ((lane >> 4) << 2) + r4;
        const int col = wc * 32 + ni * 16 + (lane & 15);
        ctile[row * 128 + (col ^ (((row >> 2) & 1) << 4))] = acc[mi][ni][r4];
      }
    }
  }
  __syncthreads();
  // read back float4/lane; add prefetched hid + b2, stream out (coalesced)
  #pragma unroll
  for (int i = 0; i < 8; ++i) {
    const int idx = i * 512 + t;           // 0..4095 float4 slots
    const int row = idx >> 5;              // 0..127
    const int j0  = (idx & 31) << 2;       // col start (multiple of 4)
    const int swz = ((row >> 2) & 1) << 4;
    const f32x4 a = *(const f32x4*)&ctile[row * 128 + (j0 ^ swz)];
    const f32x4 bias = *(const f32x4*)(b2 + bn + j0);
    const size_t gidx = (size_t)(bm + row) * D_ + bn + j0;
    f32x4 o;
    o.x = hp[i].x + a.x + bias.x;
    o.y = hp[i].y + a.y + bias.y;
    o.z = hp[i].z + a.z + bias.z;
    o.w = hp[i].w + a.w + bias.w;
    __builtin_nontemporal_store(o, (f32x4*)(out + gidx));
  }
}

extern "C" void kernel_launch(void* const* d_in, const int* in_sizes, int n_in,
                              void* d_out, int out_size, void* d_ws, size_t ws_size,
                              hipStream_t stream) {
  const float* hid  = (const float*)d_in[0];
  const float* lnw  = (const float*)d_in[1];
  const float* lnb  = (const float*)d_in[2];
  const float* W    = (const float*)d_in[3];
  const float* bias = (const float*)d_in[4];
  const int*   s3   = (const int*)d_in[5];
  const int*   s5   = (const int*)d_in[6];
  float* out = (float*)d_out;

  // workspace layout (every byte written by k_pre; no memset needed):
  //   [0, 1MB)         W2b  bf16 [1024][512]
  //   [1MB, +4KB)      b2   fp32 [1024]
  //   [1MB+4KB, +32MB) g    bf16 [32768][512]
  char* ws = (char*)d_ws;
  __hip_bfloat16* w2b = (__hip_bfloat16*)ws;
  float*          b2  = (float*)(ws + 1048576);
  __hip_bfloat16* g   = (__hip_bfloat16*)(ws + 1052672);

  k_pre <<<dim3(1024 + N_), dim3(256), 0, stream>>>(hid, lnw, lnb, s3, W, bias, s5,
                                                    g, w2b, b2);
  k_gemm<<<dim3(2048),      dim3(512), 0, stream>>>(g, w2b, b2, hid, out);
}

// Round 14
// 106.811 us; speedup vs baseline: 1.3783x; 1.3783x over previous
//
#include <hip/hip_runtime.h>
#include <hip/hip_bf16.h>
#include <stdint.h>

#define LN_EPS 1e-5f

typedef __attribute__((ext_vector_type(4))) float f32x4;
typedef __attribute__((ext_vector_type(8))) short bf16x8;

#define D_ 1024
#define P_ 512
#define N_ 32768   // B*S rows

// async global->LDS, 16B per lane
__device__ __forceinline__ void gload_lds16(const void* gsrc, void* ldst) {
  __builtin_amdgcn_global_load_lds(
      (const __attribute__((address_space(1))) void*)gsrc,
      (__attribute__((address_space(3))) void*)ldst,
      16, 0, 0);
}

__device__ __forceinline__ short f2bf(float x) {
  union { __hip_bfloat16 h; short s; } u; u.h = __float2bfloat16(x); return u.s;
}

// ---------------- fused pre-kernel: [0,1024) = W2 build, [1024,33792) = LN ----------------
// W2 path (block c): s5 partitions d-space (each d maps to exactly one c), so
// block c finds its own d-list with a parallel LDS scan (4 d's/thread, LDS
// atomics -> <=32 entries), then sums the matching W rows coalesced and writes
// w2b (bf16) + b2 directly. W is read exactly once device-wide. No global
// atomics, no memset, no fp32 intermediate buffer.
// LN path (block 1024+n): identical to the proven round-6 k_ln_gather.
// The 1024 W2 blocks dispatch first and hide under the 32768-block LN stream.
__global__ __launch_bounds__(256) void k_pre(
    const float* __restrict__ x,      // hidden_states [N_,D_]
    const float* __restrict__ lnw, const float* __restrict__ lnb,
    const int* __restrict__ s3,
    const float* __restrict__ W,      // [D_,P_]
    const float* __restrict__ bias,   // [D_]
    const int* __restrict__ s5,       // [D_]
    __hip_bfloat16* __restrict__ g,   // out: [N_,P_]
    __hip_bfloat16* __restrict__ w2b, // out: [D_,P_]
    float* __restrict__ b2) {         // out: [D_]
  __shared__ int ibuf[1024];          // s5 copy (w2 path) / f32 row (ln path)
  __shared__ float psum[4], psum2[4];
  __shared__ int list[32];
  __shared__ int cnt;
  const int bid = blockIdx.x;
  const int t = threadIdx.x;

  if (bid < 1024) {
    // ===== W2 build path =====
    const int c = bid;
    if (t == 0) cnt = 0;
    #pragma unroll
    for (int i = 0; i < 4; ++i) ibuf[t + i * 256] = s5[t + i * 256];
    __syncthreads();
    #pragma unroll
    for (int i = 0; i < 4; ++i) {
      const int d = t + i * 256;
      if (ibuf[d] == c) { const int p = atomicAdd(&cnt, 1); list[p] = d; }
    }
    __syncthreads();
    const int k = cnt;
    float a0 = 0.f, a1 = 0.f, bb = 0.f;
    for (int j = 0; j < k; ++j) {
      const int d = list[j];
      const float2 wv = ((const float2*)(W + (size_t)d * P_))[t];  // cols 2t,2t+1
      a0 += wv.x; a1 += wv.y; bb += bias[d];
    }
    const unsigned lo = (unsigned short)f2bf(a0);
    const unsigned hi = (unsigned short)f2bf(a1);
    ((unsigned int*)w2b)[c * 256 + t] = lo | (hi << 16);
    if (t == 0) b2[c] = bb;
  } else {
    // ===== LayerNorm + gather path (round-6 proven) =====
    const int n = bid - 1024;
    float* row = (float*)ibuf;
    const float* xr = x + (size_t)n * D_;
    float4 v = ((const float4*)xr)[t];     // 256 threads * 4 floats = 1024
    ((float4*)row)[t] = v;
    float s  = v.x + v.y + v.z + v.w;
    float s2 = v.x*v.x + v.y*v.y + v.z*v.z + v.w*v.w;
    #pragma unroll
    for (int off = 32; off > 0; off >>= 1) {
      s  += __shfl_down(s, off);
      s2 += __shfl_down(s2, off);
    }
    const int lane = t & 63, wid = t >> 6;
    if (lane == 0) { psum[wid] = s; psum2[wid] = s2; }
    __syncthreads();
    const float tot  = psum[0] + psum[1] + psum[2] + psum[3];
    const float tot2 = psum2[0] + psum2[1] + psum2[2] + psum2[3];
    const float mu  = tot * (1.f / D_);
    const float var = tot2 * (1.f / D_) - mu * mu;
    const float inv = rsqrtf(var + LN_EPS);
    __hip_bfloat16* gr = g + (size_t)n * P_;
    const int i0 = s3[2*t], i1 = s3[2*t+1];
    const float v0 = (row[i0] - mu) * inv * lnw[i0] + lnb[i0];
    const float v1 = (row[i1] - mu) * inv * lnw[i1] + lnb[i1];
    const unsigned lo = (unsigned short)f2bf(v0);
    const unsigned hi = (unsigned short)f2bf(v1);
    ((unsigned int*)gr)[t] = lo | (hi << 16);
  }
}

// ---------------- kernel: bf16 MFMA GEMM + residual + bias ----------------
// out[n,c] = hid[n,c] + sum_p g[n,p]*W2[c,p] + b2[c]
// ROUND-10 CONFIG (measured best, 107.3 us total):
// 128x128 tile, BK=64, double-buffered LDS (64KB), 8 waves (2x4, 64x32 wave
// tile), 16x16x32 bf16 MFMA, acc 4x2. 2-phase schedule: one barrier per
// K-step; STAGE(ks+1) issued right after the barrier so its vmcnt drain (at
// the NEXT barrier) hides under this step's ds_read + 32 MFMA.
// hid epilogue tile prefetched 2 f32x4/thread at ks=4..7 -- SHORT live
// ranges (r13 lesson: issuing all 8 up front spills hp to scratch at
// VGPR=64 -> +134MB HBM).
// Epilogue: acc tile bounced through the dead 64KB LDS (128x128 f32), read
// back float4/lane -> out-store fully coalesced.
#define BM 128
#define BN 128
#define BK 64

__global__ __launch_bounds__(512, 4) void k_gemm(
    const __hip_bfloat16* __restrict__ g,    // [N_,P_]
    const __hip_bfloat16* __restrict__ w2b,  // [D_,P_]
    const float* __restrict__ b2,            // [D_]
    const float* __restrict__ hid,           // [N_,D_]
    float* __restrict__ out) {               // [N_,D_]
  __shared__ __align__(16) char smem[65536]; // At[2][16K] | Bt[2][16K] == ctile f32[128][128]
  char* At[2] = { smem,         smem + 16384 };
  char* Bt[2] = { smem + 32768, smem + 49152 };
  float* ctile = (float*)smem;

  // XCD-aware swizzle (proven: FETCH 202->132 MB): XCD x gets 32 contiguous
  // bm strips; the 8 bn-siblings of each strip stay on one XCD.
  const int bid = blockIdx.x;                // 0..2047
  const int x = bid & 7;
  const int kq = bid >> 3;                   // 0..255
  const int bm = (x * 32 + (kq >> 3)) * BM;
  const int bn = (kq & 7) * BN;

  const int t = threadIdx.x;
  const int lane = t & 63;
  const int wid = t >> 6;                    // 8 waves
  const int wr = wid >> 2, wc = wid & 3;     // 2x4 waves, 64x32 subtile each

  f32x4 acc[4][2] = {};
  f32x4 hp[8];                               // prefetched hid tile (32 VGPR)

  // stage tile ks into buf: 1024 chunks of 16B per operand, 2 per thread each
  #define STAGE(ks, buf)                                                      \
    {                                                                         \
      const int k0 = (ks) * BK;                                               \
      _Pragma("unroll")                                                       \
      for (int i = 0; i < 2; ++i) {                                           \
        int ch = t + i * 512;                 /* 0..1023 */                    \
        int r  = ch >> 3;                     /* tile row, 8 x 16B per 128B row */ \
        int cc = ch & 7;                                                      \
        int col = ((cc ^ (r & 7)) << 3);      /* pre-swizzled src col (bf16) */ \
        gload_lds16(g   + (size_t)(bm + r) * P_ + k0 + col, At[buf] + ch * 16); \
        gload_lds16(w2b + (size_t)(bn + r) * P_ + k0 + col, Bt[buf] + ch * 16); \
      }                                                                       \
    }

  STAGE(0, 0);
  #pragma unroll
  for (int ks = 0; ks < 8; ++ks) {
    const int buf = ks & 1;
    __syncthreads();                   // drains the stage issued last iter
    if (ks < 7) STAGE(ks + 1, buf ^ 1);  // latency hides under this compute

    // hid prefetch: 2 f32x4/thread at ks=4..7 (compile-time indices)
    if (ks >= 4) {
      #pragma unroll
      for (int u = 0; u < 2; ++u) {
        const int i = (ks - 4) * 2 + u;
        const int idx = i * 512 + t;         // 0..4095 float4 slots
        const int row = idx >> 5;
        const int j0  = (idx & 31) << 2;
        hp[i] = __builtin_nontemporal_load(
            (const f32x4*)(hid + (size_t)(bm + row) * D_ + bn + j0));
      }
    }

    bf16x8 af[2][4], bfr[2][2];
    #pragma unroll
    for (int kk = 0; kk < 2; ++kk) {
      const int colb = kk * 64 + ((lane >> 4) << 4);   // byte offset in row
      #pragma unroll
      for (int mi = 0; mi < 4; ++mi) {
        const int r = wr * 64 + mi * 16 + (lane & 15);
        af[kk][mi] = *(const bf16x8*)(At[buf] + ((r * 128 + colb) ^ ((r & 7) << 4)));
      }
      #pragma unroll
      for (int ni = 0; ni < 2; ++ni) {
        const int r = wc * 32 + ni * 16 + (lane & 15);
        bfr[kk][ni] = *(const bf16x8*)(Bt[buf] + ((r * 128 + colb) ^ ((r & 7) << 4)));
      }
    }
    #pragma unroll
    for (int kk = 0; kk < 2; ++kk)
      #pragma unroll
      for (int mi = 0; mi < 4; ++mi)
        #pragma unroll
        for (int ni = 0; ni < 2; ++ni)
          acc[mi][ni] = __builtin_amdgcn_mfma_f32_16x16x32_bf16(
              af[kk][mi], bfr[kk][ni], acc[mi][ni], 0, 0, 0);
  }

  // ===== epilogue =====
  __syncthreads();   // all LDS reads of At/Bt done; smem becomes ctile
  // write acc fragments to ctile. C/D layout: col=lane&15, row=(lane>>4)*4+r4.
  // col-XOR ((row>>2)&1)<<4 splits the 4 lane-groups across banks 0-15/16-31
  // and preserves float4 contiguity on readback.
  #pragma unroll
  for (int ni = 0; ni < 2; ++ni) {
    #pragma unroll
    for (int mi = 0; mi < 4; ++mi) {
      #pragma unroll
      for (int r4 = 0; r4 < 4; ++r4) {
        const int row = wr * 64 + mi * 16 + ((lane >> 4) << 2) + r4;
        const int col = wc * 32 + ni * 16 + (lane & 15);
        ctile[row * 128 + (col ^ (((row >> 2) & 1) << 4))] = acc[mi][ni][r4];
      }
    }
  }
  __syncthreads();
  // read back float4/lane; add prefetched hid + b2, stream out (coalesced)
  #pragma unroll
  for (int i = 0; i < 8; ++i) {
    const int idx = i * 512 + t;           // 0..4095 float4 slots
    const int row = idx >> 5;              // 0..127
    const int j0  = (idx & 31) << 2;       // col start (multiple of 4)
    const int swz = ((row >> 2) & 1) << 4;
    const f32x4 a = *(const f32x4*)&ctile[row * 128 + (j0 ^ swz)];
    const f32x4 bias = *(const f32x4*)(b2 + bn + j0);
    const size_t gidx = (size_t)(bm + row) * D_ + bn + j0;
    f32x4 o;
    o.x = hp[i].x + a.x + bias.x;
    o.y = hp[i].y + a.y + bias.y;
    o.z = hp[i].z + a.z + bias.z;
    o.w = hp[i].w + a.w + bias.w;
    __builtin_nontemporal_store(o, (f32x4*)(out + gidx));
  }
}

extern "C" void kernel_launch(void* const* d_in, const int* in_sizes, int n_in,
                              void* d_out, int out_size, void* d_ws, size_t ws_size,
                              hipStream_t stream) {
  const float* hid  = (const float*)d_in[0];
  const float* lnw  = (const float*)d_in[1];
  const float* lnb  = (const float*)d_in[2];
  const float* W    = (const float*)d_in[3];
  const float* bias = (const float*)d_in[4];
  const int*   s3   = (const int*)d_in[5];
  const int*   s5   = (const int*)d_in[6];
  float* out = (float*)d_out;

  // workspace layout (every byte written by k_pre; no memset needed):
  //   [0, 1MB)         W2b  bf16 [1024][512]
  //   [1MB, +4KB)      b2   fp32 [1024]
  //   [1MB+4KB, +32MB) g    bf16 [32768][512]
  char* ws = (char*)d_ws;
  __hip_bfloat16* w2b = (__hip_bfloat16*)ws;
  float*          b2  = (float*)(ws + 1048576);
  __hip_bfloat16* g   = (__hip_bfloat16*)(ws + 1052672);

  k_pre <<<dim3(1024 + N_), dim3(256), 0, stream>>>(hid, lnw, lnb, s3, W, bias, s5,
                                                    g, w2b, b2);
  k_gemm<<<dim3(2048),      dim3(512), 0, stream>>>(g, w2b, b2, hid, out);
}